// Round 2
// baseline (1291.100 us; speedup 1.0000x reference)
//
#include <hip/hip_runtime.h>

// LIF layer: v_pre = a*v + (1-a)*i ; z = 10*(v_pre-0.25) ; s = (v_pre>=0.25);
// v = s ? 0 : v_pre.  One thread per (b,f) row, sequential scan over L=1024.
// Memory-bound: 384 MiB total traffic -> ~64us floor at 6.3 TB/s.
//
// Parallelism is capped at 512 waves (2 waves/CU) by the serial time scan, so
// BW must come from per-wave MLP. This version software-pipelines the input
// stream with a PF=16 rotating register buffer: the load for batch t+PF issues
// BEFORE computing batch t, keeping ~8KB/wave (~16KB/CU) of loads continuously
// in flight instead of the load-drain-compute duty cycle the plain unroll gave.
// All buf indices are compile-time (full unroll) so buf stays in VGPRs.
// NOTE: __builtin_nontemporal_* requires clang native vector types, not
// HIP_vector_type<float,4> -> use ext_vector_type(4).

constexpr int L_LEN = 1024;
constexpr int NV    = L_LEN / 4;   // 256 float4 batches per row
constexpr int PF    = 16;          // prefetch depth (16B in flight per lane)

typedef float f32x4 __attribute__((ext_vector_type(4)));

__global__ __launch_bounds__(64) void lif_kernel(
    const float* __restrict__ I, float* __restrict__ Z,
    float* __restrict__ S, int nrows)
{
#pragma clang fp contract(off)
    int row = blockIdx.x * 64 + threadIdx.x;
    if (row >= nrows) return;

    const float alpha = 0.7165313105737893f;   // exp(-1/3) rounded to f32
    const float oma   = 1.0f - alpha;
    const float thr   = 0.25f;
    const float beta  = 10.0f;

    const f32x4* in4 = reinterpret_cast<const f32x4*>(I) + (size_t)row * NV;
    f32x4*       z4  = reinterpret_cast<f32x4*>(Z)       + (size_t)row * NV;
    f32x4*       s4  = reinterpret_cast<f32x4*>(S)       + (size_t)row * NV;

    float v = 0.0f;

    // Prologue: fill the prefetch pipeline.
    f32x4 buf[PF];
#pragma unroll
    for (int k = 0; k < PF; ++k)
        buf[k] = __builtin_nontemporal_load(&in4[k]);

    auto step4 = [&](int t, f32x4 x) {
        f32x4 zo, so;
        float vp;

#pragma unroll
        for (int j = 0; j < 4; ++j) {
            vp    = alpha * v + oma * x[j];
            zo[j] = beta * (vp - thr);
            so[j] = (vp >= thr) ? 1.0f : 0.0f;
            v     = (vp >= thr) ? 0.0f : vp;
        }

        __builtin_nontemporal_store(zo, &z4[t]);
        __builtin_nontemporal_store(so, &s4[t]);
    };

    // Main loop: issue load t+PF before computing batch t. With unroll PF the
    // (t & (PF-1)) indices are compile-time constants -> buf stays in registers.
#pragma unroll PF
    for (int t = 0; t < NV - PF; ++t) {
        f32x4 x = buf[t & (PF - 1)];
        buf[t & (PF - 1)] = __builtin_nontemporal_load(&in4[t + PF]);
        step4(t, x);
    }

    // Epilogue: drain the last PF batches (fully unrolled, constant indices).
#pragma unroll
    for (int t = NV - PF; t < NV; ++t) {
        f32x4 x = buf[t & (PF - 1)];
        step4(t, x);
    }
}

extern "C" void kernel_launch(void* const* d_in, const int* in_sizes, int n_in,
                              void* d_out, int out_size, void* d_ws, size_t ws_size,
                              hipStream_t stream) {
    const float* I = (const float*)d_in[0];
    int n_elems = in_sizes[0];          // B*F*L = 33554432
    int nrows   = n_elems / L_LEN;      // B*F   = 32768

    float* Z = (float*)d_out;                       // first output, flat (B,F,L)
    float* S = (float*)d_out + (size_t)n_elems;     // second output

    int block = 64;                                  // 512 blocks -> 2 waves/CU on all 256 CUs
    int grid  = (nrows + block - 1) / block;
    lif_kernel<<<grid, block, 0, stream>>>(I, Z, S, nrows);
}

// Round 3
// 409.035 us; speedup vs baseline: 3.1565x; 3.1565x over previous
//
#include <hip/hip_runtime.h>

// LIF layer: v_pre = a*v + (1-a)*i ; z = 10*(v_pre-0.25) ; s = (v_pre>=0.25);
// v = s ? 0 : v_pre.  One thread per (b,f) row, sequential scan over L=1024.
// Memory-bound: 384 MiB total traffic -> ~64us floor at 6.3 TB/s.
//
// Parallelism is capped at 512 waves (2 waves/CU) by the serial time scan, so
// BW must come from per-wave MLP. PF=16 rotating register prefetch: the load
// for batch t+PF issues BEFORE computing batch t (~8KB/wave in flight).
// All buf indices are compile-time constants (unroll PF, rule #20).
//
// ROUND-2 LESSON: do NOT use __builtin_nontemporal_store here. nt stores are
// L2 no-allocate on gfx950 -> 16B lane-stores lose L2 write coalescing into
// 64B HBM sectors (WRITE_SIZE 268MB -> 880MB, 3.3x) and store completion goes
// to HBM, strangling vmcnt waits (kernel 89us -> 1047us). Default cache
// policy restored on both loads and stores.

constexpr int L_LEN = 1024;
constexpr int NV    = L_LEN / 4;   // 256 float4 batches per row
constexpr int PF    = 16;          // prefetch depth (16B in flight per lane)

typedef float f32x4 __attribute__((ext_vector_type(4)));

__global__ __launch_bounds__(64) void lif_kernel(
    const float* __restrict__ I, float* __restrict__ Z,
    float* __restrict__ S, int nrows)
{
#pragma clang fp contract(off)
    int row = blockIdx.x * 64 + threadIdx.x;
    if (row >= nrows) return;

    const float alpha = 0.7165313105737893f;   // exp(-1/3) rounded to f32
    const float oma   = 1.0f - alpha;
    const float thr   = 0.25f;
    const float beta  = 10.0f;

    const f32x4* in4 = reinterpret_cast<const f32x4*>(I) + (size_t)row * NV;
    f32x4*       z4  = reinterpret_cast<f32x4*>(Z)       + (size_t)row * NV;
    f32x4*       s4  = reinterpret_cast<f32x4*>(S)       + (size_t)row * NV;

    float v = 0.0f;

    // Prologue: fill the prefetch pipeline.
    f32x4 buf[PF];
#pragma unroll
    for (int k = 0; k < PF; ++k)
        buf[k] = in4[k];

    auto step4 = [&](int t, f32x4 x) {
        f32x4 zo, so;
        float vp;

#pragma unroll
        for (int j = 0; j < 4; ++j) {
            vp    = alpha * v + oma * x[j];
            zo[j] = beta * (vp - thr);
            so[j] = (vp >= thr) ? 1.0f : 0.0f;
            v     = (vp >= thr) ? 0.0f : vp;
        }

        z4[t] = zo;
        s4[t] = so;
    };

    // Main loop: issue load t+PF before computing batch t. With unroll PF the
    // (t & (PF-1)) indices are compile-time constants -> buf stays in VGPRs.
#pragma unroll PF
    for (int t = 0; t < NV - PF; ++t) {
        f32x4 x = buf[t & (PF - 1)];
        buf[t & (PF - 1)] = in4[t + PF];
        step4(t, x);
    }

    // Epilogue: drain the last PF batches (fully unrolled, constant indices).
#pragma unroll
    for (int t = NV - PF; t < NV; ++t) {
        f32x4 x = buf[t & (PF - 1)];
        step4(t, x);
    }
}

extern "C" void kernel_launch(void* const* d_in, const int* in_sizes, int n_in,
                              void* d_out, int out_size, void* d_ws, size_t ws_size,
                              hipStream_t stream) {
    const float* I = (const float*)d_in[0];
    int n_elems = in_sizes[0];          // B*F*L = 33554432
    int nrows   = n_elems / L_LEN;      // B*F   = 32768

    float* Z = (float*)d_out;                       // first output, flat (B,F,L)
    float* S = (float*)d_out + (size_t)n_elems;     // second output

    int block = 64;                                  // 512 blocks -> 2 waves/CU on all 256 CUs
    int grid  = (nrows + block - 1) / block;
    lif_kernel<<<grid, block, 0, stream>>>(I, Z, S, nrows);
}